// Round 18
// baseline (276.443 us; speedup 1.0000x reference)
//
#include <hip/hip_runtime.h>
#include <cstddef>
#include <cstdint>

typedef unsigned short u16;
typedef unsigned int u32;
typedef __attribute__((ext_vector_type(8))) short short8;   // 8 bf16 (4 VGPRs)
typedef __attribute__((ext_vector_type(4))) float f32x4;    // 4 fp32 acc

#define NB 8
#define NR 128
#define NPOS 49
#define EPSV 1e-5f
#define NSLOT 512

// d_out (fp32): er_c [8,1,128,4] | out_c [8,128,32,7,7] | keep_count [8]
#define OUT_OC   4096
#define OUT_KEEP 1609728

// workspace (bytes) — proven footprint
static constexpr size_t OFF_META = 256;
static constexpr size_t OFF_KEEP = 33024;                      // int keepd[8]
static constexpr size_t OFF_W1Q  = 40960;                      // bf16 frag W1 (4.72 MB)
static constexpr size_t OFF_W2Q  = OFF_W1Q + 4718592;          // bf16 frag W2 (1.18 MB)
static constexpr size_t OFF_W3   = OFF_W2Q + 1179648;          // u16 frag W3 (16 KB region)
static constexpr size_t OFF_X1S  = OFF_W3  + 32768;            // UNION: S f32 (13.1MB) then x1 u16 [512][4][49][64]
static constexpr size_t OFF_AP   = OFF_X1S + 13107200;         // Apool u16 [512][16][49][64]
static constexpr size_t WS_NEED  = OFF_AP  + 51380224;

static __device__ __forceinline__ u16 f2bf(float f) {
  union { float f; u32 u; } x; x.f = f;
  u32 r = 0x7fffu + ((x.u >> 16) & 1u);
  return (u16)((x.u + r) >> 16);
}

// ================= merged preprocessing: k_int | W1 pack | W2 pack | W3 pack | setup
__device__ __forceinline__ void int_body(const float* __restrict__ feat, float* __restrict__ S,
                                         int b, int cg, float* F)
{
  int tid = threadIdx.x;
  const float* fb = feat + ((size_t)b * 1024 + cg * 64) * 361;
#pragma unroll 1
  for (int i = tid; i < 64 * 361; i += 256) F[i] = fb[i];
  __syncthreads();
  if (tid < 64) {
    int ch = tid;
    const float* fp = F + ch * 361;
    float* Sp = S + (size_t)b * 400 * 1024 + cg * 64 + ch;
    float prev[20];
#pragma unroll
    for (int w = 0; w < 20; ++w) { prev[w] = 0.f; Sp[(size_t)w * 1024] = 0.f; }
    for (int h = 0; h < 19; ++h) {
      float run = 0.f;
      float* Sr = Sp + (size_t)(h + 1) * 20 * 1024;
      Sr[0] = 0.f;
#pragma unroll
      for (int w = 0; w < 19; ++w) {
        run += fp[h * 19 + w];
        float v = run + prev[w + 1];
        Sr[(size_t)(w + 1) * 1024] = v;
        prev[w + 1] = v;
      }
    }
  }
}

__device__ __forceinline__ void packw_body(const float* __restrict__ W, u16* __restrict__ wq,
                                           int IC, int c, int og, float* F)
{
  int tid = threadIdx.x, oc0 = og * 32;
#pragma unroll 1
  for (int i = tid; i < 18432; i += 256) {
    int ocr = i / 576, r = i - ocr * 576;
    F[i] = W[(size_t)(oc0 + ocr) * IC * 9 + c * 576 + r];
  }
  __syncthreads();
#pragma unroll 1
  for (int w = tid; w < 18432; w += 256) {
    int j = w & 7, lane = (w >> 3) & 63, rest = w >> 9;
    int ntr = rest & 1, kk = rest >> 1;
    int k9i = kk >> 1, ks = kk & 1;
    int ocr = ntr * 16 + (lane & 15);
    int icr = ks * 32 + ((lane >> 4) & 3) * 8 + j;
    int bid_ = (c * 9 + k9i) * 2 + ks;
    wq[((size_t)bid_ * 1024 + (oc0 / 16 + ntr) * 64 + lane) * 8 + j] = f2bf(F[ocr * 576 + icr * 9 + k9i]);
  }
}

__global__ __launch_bounds__(256) void k_prep(
    const float* __restrict__ feat, float* __restrict__ S,
    const float* __restrict__ W1, const float* __restrict__ W2, const float* __restrict__ W3,
    u16* __restrict__ w1q, u16* __restrict__ w2q, u16* __restrict__ w3q,
    const float* __restrict__ roi, int* __restrict__ cnt,
    int* __restrict__ meta, int* __restrict__ keepd, float* __restrict__ out)
{
  __shared__ float SH[23104];                      // 92.4 KB union
  int bx = blockIdx.x;
  if (bx < 128) { int_body(feat, S, bx >> 4, bx & 15, SH); return; }
  if (bx < 256) { packw_body(W1, w1q, 1024, (bx - 128) >> 3, (bx - 128) & 7, SH); return; }
  if (bx < 288) { packw_body(W2, w2q, 256, (bx - 256) >> 3, (bx - 256) & 7, SH); return; }
  if (bx == 288) {                                 // W3 frag pack (verified R7)
    for (int i = threadIdx.x; i < 8192; i += 256) {
      int oc = i >> 8, ic = i & 255;
      int kk = ic >> 5;
      int lane = ((ic >> 3) & 3) * 16 + (oc & 15);
      int nt16 = oc >> 4;
      int j = ic & 7;
      w3q[((size_t)((kk * 2 + nt16) * 64) + lane) * 8 + j] = f2bf(W3[i]);
    }
    return;
  }
  // setup (8 blocks), 256 threads, work on t<128
  int b = bx - 289, t = threadIdx.x;
  int* sval = (int*)SH;
  int* spre = sval + 128;
  int rl[4], cl[4], valid = 0;
  if (t < 128) {
    const float* rp = roi + (size_t)(b * NR + t) * 5;
#pragma unroll
    for (int j = 0; j < 4; ++j) {
      rl[j] = (int)(rp[1 + j] * 18.75f);
      cl[j] = min(max(rl[j], 0), 18);
    }
    valid = (cl[2] > cl[0]) && (cl[3] > cl[1]) ? 1 : 0;
    sval[t] = valid;
  }
  __syncthreads();
  if (t == 0) {
    int s = 0;
    for (int i = 0; i < 128; ++i) { spre[i] = s; s += sval[i]; }
    spre[128] = s;
    keepd[b] = s;
    out[OUT_KEEP + b] = (float)s;
  }
  __syncthreads();
  if (t < 128) {
    int keep = spre[128];
    if (valid) {
      int dst = spre[t];
      int slot = atomicAdd(cnt, 1);
      int* mt = meta + slot * 8;
      mt[0] = b; mt[1] = dst;
      mt[2] = cl[1]; mt[3] = cl[3];
      mt[4] = cl[0]; mt[5] = cl[2];
#pragma unroll
      for (int j = 0; j < 4; ++j)
        out[(size_t)(b * NR + dst) * 4 + j] = (float)rl[j] * (16.0f / 300.0f);
    }
    if (t >= keep) {
#pragma unroll
      for (int j = 0; j < 4; ++j) out[(size_t)(b * NR + t) * 4 + j] = 0.f;
    }
  }
}

// ---------------- k_pool: pool each valid slot ONCE -> Apool[slot][16][49][64] bf16
__global__ __launch_bounds__(256) void k_pool(
    const int* __restrict__ cnt, const int* __restrict__ meta,
    const float* __restrict__ S, u16* __restrict__ Apool)
{
  int cv = *cnt; if (cv > NSLOT) cv = NSLOT;
  int slot = blockIdx.x;
  if (slot >= cv) return;
  const int* mt_ = meta + slot * 8;
  int b = mt_[0], ylo = mt_[2], yhi = mt_[3], xlo = mt_[4], xhi = mt_[5];
  int Hy = yhi - ylo + 1, Hx = xhi - xlo + 1;
  const float* Sb = S + (size_t)b * 400 * 1024;
  u16* Ap = Apool + (size_t)slot * 50176;
  int base = blockIdx.y * 12544, end = base + 12544;
  int tid = threadIdx.x;
#pragma unroll 1
  for (int t0 = base + tid; t0 < end; t0 += 1024) {
#pragma unroll
    for (int u = 0; u < 4; ++u) {
      int t = t0 + u * 256;
      if (t < end) {
        int ch = t & 63, r = t >> 6;
        int bin = r % 49, c = r / 49;
        int p = bin / 7, q = bin - 7 * p;
        int sy = (p * Hy) / 7, ey = ((p + 1) * Hy + 6) / 7;
        int sx = (q * Hx) / 7, ex = ((q + 1) * Hx + 6) / 7;
        int y0 = ylo + sy, y1 = ylo + ey, x0 = xlo + sx, x1 = xlo + ex;
        const float* Sc = Sb + c * 64 + ch;
        float v = Sc[(size_t)(y1 * 20 + x1) * 1024] - Sc[(size_t)(y0 * 20 + x1) * 1024]
                - Sc[(size_t)(y1 * 20 + x0) * 1024] + Sc[(size_t)(y0 * 20 + x0) * 1024];
        v /= (float)((ey - sy) * (ex - sx));
        Ap[(size_t)c * 3136 + bin * 64 + ch] = f2bf(v);
      }
    }
  }
}

// packed A-fragment offsets for a [50][STR] panel (zero row 49)
template<int STR>
__device__ __forceinline__ void build_aoffp(int n, int kq, int (&aoffp)[9][2]) {
#pragma unroll
  for (int t9 = 0; t9 < 9; ++t9) {
    int off[4];
#pragma unroll
    for (int mt = 0; mt < 4; ++mt) {
      int lm = mt * 16 + n;
      int mv = lm < 49;
      int lm2 = mv ? lm : 0;
      int p = lm2 / 7, q = lm2 - 7 * p;
      int ky = t9 / 3, kx = t9 - 3 * (t9 / 3);
      int ry = p + ky - 1, rx = q + kx - 1;
      int ok = mv && ry >= 0 && ry < 7 && rx >= 0 && rx < 7;
      int rr = ok ? ry * 7 + rx : 49;
      off[mt] = rr * STR + kq * 8;
    }
    aoffp[t9][0] = (off[0] & 0xFFFF) | (off[1] << 16);
    aoffp[t9][1] = (off[2] & 0xFFFF) | (off[3] << 16);
  }
}

// ================= conv1: 4 ROIs x 64 oc; 12 waves (768 thr, VGPR cap 170 -> acc[4][4]
// fits, no spill) = roi4 x kh3 (chunks {6,5,5}); each A-read feeds 4 MFMA (A-LDS halved).
__global__ __launch_bounds__(768) void k_conv1(
    const int* __restrict__ cnt, const u16* __restrict__ Apool, const u16* __restrict__ wq,
    const float* __restrict__ bb, const float* __restrict__ gg, const float* __restrict__ bec,
    const float* __restrict__ mm, const float* __restrict__ vv,
    u16* __restrict__ x1)
{
  int cv = *cnt; if (cv > NSLOT) cv = NSLOT;
  int slot0 = blockIdx.x * 4, ocq = blockIdx.y;     // ocq in [0,4): 64 oc each
  if (slot0 >= cv) return;

  __shared__ __align__(16) char smem[100352];
  u16* panels = (u16*)smem;                 // [kh3][roi4][50][72] = 86.4 KB
  float* red1 = (float*)smem;               // [4][49][64] = 50.2 KB (panels dead)
  float* red2 = (float*)(smem + 50176);

  int tid = threadIdx.x, lane = tid & 63, wave = tid >> 6;   // 12 waves
  int roi4 = wave & 3, kh = wave >> 2;      // kh in 0..2
  int n = lane & 15, kq = lane >> 4;
  const int cbase = (kh == 0) ? 0 : (kh == 1 ? 6 : 11);
  const int ccnt  = (kh == 0) ? 6 : 5;

  for (int i = tid; i < 12 * 36; i += 768) {        // zero row 49 of all 12 sub-panels
    int sp = i / 36, w2 = i - sp * 36;
    ((u32*)(panels + sp * 3600 + 49 * 72))[w2] = 0;
  }

  int aoffp[9][2];
  build_aoffp<72>(n, kq, aoffp);
  f32x4 acc[4][4];
#pragma unroll
  for (int i = 0; i < 4; ++i)
#pragma unroll
    for (int j = 0; j < 4; ++j) acc[i][j] = (f32x4){0.f, 0.f, 0.f, 0.f};

  const u16* pf = wq + (size_t)(ocq * 4) * 512 + (size_t)lane * 8 + (size_t)cbase * 18 * 8192;
  short8 bbuf[2][4];
#pragma unroll
  for (int nt = 0; nt < 4; ++nt) bbuf[0][nt] = *(const short8*)(pf + nt * 512);
#pragma unroll
  for (int nt = 0; nt < 4; ++nt) bbuf[1][nt] = *(const short8*)(pf + 8192 + nt * 512);
  pf += (size_t)2 * 8192;

  // stage round nr: chunk cbase[kh3]+nr into panel[kh3][roi] (guarded per kh3)
  auto stage = [&](int nr) {
#pragma unroll 1
    for (int t = tid; t < 4704; t += 768) {
      int kh3 = t / 1568, e2 = t - kh3 * 1568;
      int rr = e2 / 392, e = e2 - rr * 392;
      int cn = (kh3 == 0) ? 6 : 5;
      if (nr < cn) {
        int c = ((kh3 == 0) ? 0 : (kh3 == 1 ? 6 : 11)) + nr;
        int sl = slot0 + rr; if (sl >= cv) sl = cv - 1;
        uint4 v = *((const uint4*)(Apool + ((size_t)sl * 16 + c) * 3136) + e);
        *(uint4*)(panels + (size_t)(kh3 * 4 + rr) * 3600 + (e >> 3) * 72 + (e & 7) * 8) = v;
      }
    }
  };

  stage(0);
  __syncthreads();

  const u16* P = panels + (size_t)(kh * 4 + roi4) * 3600;
#pragma unroll 1
  for (int r = 0; r < 6; ++r) {
    if (r < ccnt) {
#pragma unroll
      for (int kk = 0; kk < 18; ++kk) {
        int t9 = kk >> 1, ks = kk & 1;
        short8 bfr[4], afr[4];
#pragma unroll
        for (int nt = 0; nt < 4; ++nt) bfr[nt] = bbuf[kk & 1][nt];
#pragma unroll
        for (int nt = 0; nt < 4; ++nt) bbuf[kk & 1][nt] = *(const short8*)(pf + nt * 512);
        pf += 8192;                                 // tail overrun stays inside ws
        int coff = ks * 32;
        int o0 = (aoffp[t9][0] & 0xFFFF) + coff, o1 = (int)((u32)aoffp[t9][0] >> 16) + coff;
        int o2 = (aoffp[t9][1] & 0xFFFF) + coff, o3 = (int)((u32)aoffp[t9][1] >> 16) + coff;
        afr[0] = *(const short8*)(P + o0); afr[1] = *(const short8*)(P + o1);
        afr[2] = *(const short8*)(P + o2); afr[3] = *(const short8*)(P + o3);
#pragma unroll
        for (int mt = 0; mt < 4; ++mt)
#pragma unroll
          for (int nt = 0; nt < 4; ++nt)
            acc[mt][nt] = __builtin_amdgcn_mfma_f32_16x16x32_bf16(afr[mt], bfr[nt], acc[mt][nt], 0, 0, 0);
      }
    }
    __syncthreads();                                // all waves done with current panels
    if (r + 1 < 6) {
      stage(r + 1);
      __syncthreads();                              // next panels ready
    }
  }

  // 3-way K reduction: kh1->red1, kh2->red2; kh0 adds both + BN + store
  if (kh == 1 || kh == 2) {
    float* rd = (kh == 1) ? red1 : red2;
#pragma unroll
    for (int nt = 0; nt < 4; ++nt)
#pragma unroll
      for (int mt = 0; mt < 4; ++mt)
#pragma unroll
        for (int r = 0; r < 4; ++r) {
          int m = mt * 16 + kq * 4 + r;
          if (m < 49) rd[((size_t)roi4 * 49 + m) * 64 + nt * 16 + n] = acc[mt][nt][r];
        }
  }
  __syncthreads();
  if (kh == 0) {
    int slot = slot0 + roi4;
    if (slot < cv) {
#pragma unroll
      for (int nt = 0; nt < 4; ++nt) {
        int oc = ocq * 64 + nt * 16 + n;
        float sc = gg[oc] * rsqrtf(vv[oc] + EPSV);
        float sh = (bb[oc] - mm[oc]) * sc + bec[oc];
#pragma unroll
        for (int mt = 0; mt < 4; ++mt)
#pragma unroll
          for (int r = 0; r < 4; ++r) {
            int m = mt * 16 + kq * 4 + r;
            if (m < 49) {
              size_t ix = ((size_t)roi4 * 49 + m) * 64 + nt * 16 + n;
              float y = acc[mt][nt][r] + red1[ix] + red2[ix];
              y = fmaf(y, sc, sh);
              x1[((size_t)slot * 4 + ocq) * 3136 + m * 64 + (oc & 63)] = f2bf(y > 0.f ? y : 0.f);
            }
          }
      }
    }
  }
}

// ================= conv2+conv3 fused (R17-proven 16-wave) + zero-fill duty
__global__ __launch_bounds__(1024) void k_conv23(
    const int* __restrict__ cnt, const int* __restrict__ meta, const int* __restrict__ keepd,
    const u16* __restrict__ x1, const u16* __restrict__ w2q, const u16* __restrict__ w3q,
    const float* __restrict__ b2, const float* __restrict__ g2, const float* __restrict__ be2,
    const float* __restrict__ m2, const float* __restrict__ v2,
    const float* __restrict__ g3, const float* __restrict__ be3,
    const float* __restrict__ m3, const float* __restrict__ v3,
    float* __restrict__ out)
{
  int cv = *cnt; if (cv > NSLOT) cv = NSLOT;
  int slot = blockIdx.x;
  int tid = threadIdx.x;
  if (slot >= cv) {
    int nfill = NSLOT - cv;
#pragma unroll 1
    for (int j = slot - cv; j < 1024; j += nfill) {
      int b = j >> 7, dd = j & 127;
      if (dd >= keepd[b]) {
        float* o = out + OUT_OC + (size_t)(b * NR + dd) * 1568;
        for (int t = tid; t < 1568; t += 1024) o[t] = 0.f;
      }
    }
    return;
  }
  const int* mt_ = meta + slot * 8;
  int b = mt_[0], dst = mt_[1];

  __shared__ __align__(16) char smem[77600];
  u16*   panels = (u16*)smem;               // [4 c][50][72] = 28.8 KB
  float* red    = (float*)smem;             // [8 ng][49][32] = 50.2 KB (panels dead)
  u16*   xp     = (u16*)(smem + 51200);     // [50][264] = 26.4 KB
  float* red3   = (float*)smem;             // [8][49][32]

  int lane = tid & 63, wave = tid >> 6;     // 16 waves
  int ng = wave & 7, kh = wave >> 3;        // N-group (32 oc), K-half (2 c-chunks)
  int n = lane & 15, kq = lane >> 4;

  for (int i = tid; i < 4 * 36; i += 1024) {
    int sp = i / 36, w2 = i - sp * 36;
    ((u32*)(panels + sp * 3600 + 49 * 72))[w2] = 0;
  }
  const u16* xs = x1 + (size_t)slot * 4 * 3136;
#pragma unroll 1
  for (int t = tid; t < 1568; t += 1024) {
    int c = t / 392, e = t - c * 392;
    uint4 v = *((const uint4*)(xs + (size_t)c * 3136) + e);
    *(uint4*)(panels + (size_t)c * 3600 + (e >> 3) * 72 + (e & 7) * 8) = v;
  }

  int aoffp[9][2];
  build_aoffp<72>(n, kq, aoffp);
  f32x4 acc[4][2];
#pragma unroll
  for (int i = 0; i < 4; ++i)
#pragma unroll
    for (int j = 0; j < 2; ++j) acc[i][j] = (f32x4){0.f, 0.f, 0.f, 0.f};

  const u16* pf = w2q + (size_t)(ng * 2) * 512 + (size_t)lane * 8 + (size_t)(kh * 36) * 8192;
  short8 bbuf[2][2];
#pragma unroll
  for (int nt = 0; nt < 2; ++nt) bbuf[0][nt] = *(const short8*)(pf + nt * 512);
#pragma unroll
  for (int nt = 0; nt < 2; ++nt) bbuf[1][nt] = *(const short8*)(pf + 8192 + nt * 512);
  pf += (size_t)2 * 8192;

  __syncthreads();   // x1 panels ready

#pragma unroll 1
  for (int ci = 0; ci < 2; ++ci) {
    const u16* P = panels + (size_t)(kh * 2 + ci) * 3600;
#pragma unroll
    for (int kk = 0; kk < 18; ++kk) {
      int t9 = kk >> 1, ks = kk & 1;
      short8 bfr[2], afr[4];
#pragma unroll
      for (int nt = 0; nt < 2; ++nt) bfr[nt] = bbuf[kk & 1][nt];
#pragma unroll
      for (int nt = 0; nt < 2; ++nt) bbuf[kk & 1][nt] = *(const short8*)(pf + nt * 512);
      pf += 8192;                          // tail overrun stays inside ws
      int coff = ks * 32;
      int o0 = (aoffp[t9][0] & 0xFFFF) + coff, o1 = (int)((u32)aoffp[t9][0] >> 16) + coff;
      int o2 = (aoffp[t9][1] & 0xFFFF) + coff, o3 = (int)((u32)aoffp[t9][1] >> 16) + coff;
      afr[0] = *(const short8*)(P + o0); afr[1] = *(const short8*)(P + o1);
      afr[2] = *(const short8*)(P + o2); afr[3] = *(const short8*)(P + o3);
#pragma unroll
      for (int mt = 0; mt < 4; ++mt)
#pragma unroll
        for (int nt = 0; nt < 2; ++nt)
          acc[mt][nt] = __builtin_amdgcn_mfma_f32_16x16x32_bf16(afr[mt], bfr[nt], acc[mt][nt], 0, 0, 0);
    }
  }
  __syncthreads();   // panels dead

  if (kh == 1) {
#pragma unroll
    for (int nt = 0; nt < 2; ++nt)
#pragma unroll
      for (int mt = 0; mt < 4; ++mt)
#pragma unroll
        for (int r = 0; r < 4; ++r) {
          int m = mt * 16 + kq * 4 + r;
          if (m < 49) red[((size_t)ng * 49 + m) * 32 + nt * 16 + n] = acc[mt][nt][r];
        }
  }
  __syncthreads();
  if (kh == 0) {
#pragma unroll
    for (int nt = 0; nt < 2; ++nt) {
      int oc = ng * 32 + nt * 16 + n;
      float sc = g2[oc] * rsqrtf(v2[oc] + EPSV);
      float sh = (b2[oc] - m2[oc]) * sc + be2[oc];
#pragma unroll
      for (int mt = 0; mt < 4; ++mt)
#pragma unroll
        for (int r = 0; r < 4; ++r) {
          int m = mt * 16 + kq * 4 + r;
          if (m < 49) {
            float y = acc[mt][nt][r] + red[((size_t)ng * 49 + m) * 32 + nt * 16 + n];
            y = fmaf(y, sc, sh);
            xp[m * 264 + oc] = f2bf(y > 0.f ? y : 0.f);
          }
        }
    }
  }
  if (wave == 8) {
    for (int i = lane; i < 132; i += 64) ((u32*)(xp + 49 * 264))[i] = 0;
  }
  __syncthreads();   // x2 panel ready

  if (wave < 8) {
    f32x4 a3[4][2];
#pragma unroll
    for (int mt = 0; mt < 4; ++mt) { a3[mt][0] = (f32x4){0,0,0,0}; a3[mt][1] = (f32x4){0,0,0,0}; }
    const u16* b3 = w3q + ((size_t)(wave * 2) * 64 + lane) * 8;
    short8 bf0 = *(const short8*)(b3);
    short8 bf1 = *(const short8*)(b3 + 512);
#pragma unroll
    for (int mt = 0; mt < 4; ++mt) {
      int m = mt * 16 + n;
      int row = m < 49 ? m : 49;
      short8 a = *(const short8*)(xp + row * 264 + wave * 32 + kq * 8);
      a3[mt][0] = __builtin_amdgcn_mfma_f32_16x16x32_bf16(a, bf0, a3[mt][0], 0, 0, 0);
      a3[mt][1] = __builtin_amdgcn_mfma_f32_16x16x32_bf16(a, bf1, a3[mt][1], 0, 0, 0);
    }
#pragma unroll
    for (int nt = 0; nt < 2; ++nt)
#pragma unroll
      for (int mt = 0; mt < 4; ++mt)
#pragma unroll
        for (int r = 0; r < 4; ++r) {
          int m = mt * 16 + kq * 4 + r;
          if (m < 49) red3[((size_t)wave * 49 + m) * 32 + nt * 16 + n] = a3[mt][nt][r];
        }
  }
  __syncthreads();

  size_t ob = OUT_OC + ((size_t)(b * NR + dst) * 32) * 49;
#pragma unroll 1
  for (int t = tid; t < 1568; t += 1024) {
    int m = t >> 5, oc = t & 31;
    float s = 0.f;
#pragma unroll
    for (int w8 = 0; w8 < 8; ++w8) s += red3[((size_t)w8 * 49 + m) * 32 + oc];
    float sc = g3[oc] * rsqrtf(v3[oc] + EPSV);
    float y = fmaf(s, sc, be3[oc] - m3[oc] * sc);
    out[ob + (size_t)oc * 49 + m] = y > 0.f ? y : 0.f;
  }
}

extern "C" void kernel_launch(void* const* d_in, const int* in_sizes, int n_in,
                              void* d_out, int out_size, void* d_ws, size_t ws_size,
                              hipStream_t stream)
{
  (void)in_sizes; (void)n_in; (void)out_size;
  if (ws_size < WS_NEED) return;

  const float* roi  = (const float*)d_in[0];
  const float* feat = (const float*)d_in[1];
  const float* W1   = (const float*)d_in[2];
  const float* b1   = (const float*)d_in[3];
  const float* g1   = (const float*)d_in[4];
  const float* be1  = (const float*)d_in[5];
  const float* m1   = (const float*)d_in[6];
  const float* v1   = (const float*)d_in[7];
  const float* W2   = (const float*)d_in[8];
  const float* b2   = (const float*)d_in[9];
  const float* g2   = (const float*)d_in[10];
  const float* be2  = (const float*)d_in[11];
  const float* m2   = (const float*)d_in[12];
  const float* v2   = (const float*)d_in[13];
  const float* W3   = (const float*)d_in[14];
  const float* g3   = (const float*)d_in[15];
  const float* be3  = (const float*)d_in[16];
  const float* m3   = (const float*)d_in[17];
  const float* v3   = (const float*)d_in[18];

  char* ws    = (char*)d_ws;
  int*  cnt   = (int*)ws;
  int*  meta  = (int*)(ws + OFF_META);
  int*  keepd = (int*)(ws + OFF_KEEP);
  u16*  w1q   = (u16*)(ws + OFF_W1Q);
  u16*  w2q   = (u16*)(ws + OFF_W2Q);
  u16*  w3q   = (u16*)(ws + OFF_W3);
  float* S    = (float*)(ws + OFF_X1S);
  u16*  x1    = (u16*)(ws + OFF_X1S);     // x1 overwrites S after k_pool
  u16*  Apool = (u16*)(ws + OFF_AP);
  float* out  = (float*)d_out;

  hipMemsetAsync(cnt, 0, 4, stream);

  k_prep<<<297, 256, 0, stream>>>(feat, S, W1, W2, W3, w1q, w2q, w3q,
                                  roi, cnt, meta, keepd, out);
  k_pool<<<dim3(NSLOT, 4), 256, 0, stream>>>(cnt, meta, S, Apool);
  k_conv1<<<dim3(NSLOT / 4, 4), 768, 0, stream>>>(cnt, Apool, w1q, b1, g1, be1, m1, v1, x1);
  k_conv23<<<NSLOT, 1024, 0, stream>>>(cnt, meta, keepd, x1, w2q, w3q,
                                       b2, g2, be2, m2, v2, g3, be3, m3, v3, out);
}

// Round 20
// 253.086 us; speedup vs baseline: 1.0923x; 1.0923x over previous
//
#include <hip/hip_runtime.h>
#include <cstddef>
#include <cstdint>

typedef unsigned short u16;
typedef unsigned int u32;
typedef __attribute__((ext_vector_type(8))) short short8;   // 8 bf16 (4 VGPRs)
typedef __attribute__((ext_vector_type(4))) float f32x4;    // 4 fp32 acc

#define NB 8
#define NR 128
#define NPOS 49
#define EPSV 1e-5f
#define NSLOT 512

// d_out (fp32): er_c [8,1,128,4] | out_c [8,128,32,7,7] | keep_count [8]
#define OUT_OC   4096
#define OUT_KEEP 1609728

// workspace (bytes) — proven footprint
static constexpr size_t OFF_META = 256;
static constexpr size_t OFF_KEEP = 33024;                      // int keepd[8], cnt at ws+0
static constexpr size_t OFF_W1Q  = 40960;                      // bf16 frag W1 (4.72 MB)
static constexpr size_t OFF_W2Q  = OFF_W1Q + 4718592;          // bf16 frag W2 (1.18 MB)
static constexpr size_t OFF_W3   = OFF_W2Q + 1179648;          // u16 frag W3 (16 KB region)
static constexpr size_t OFF_X1S  = OFF_W3  + 32768;            // UNION: S f32 (13.1MB) then x1 u16 [512][4][49][64]
static constexpr size_t OFF_AP   = OFF_X1S + 13107200;         // Apool u16 [512][16][49][64]
static constexpr size_t WS_NEED  = OFF_AP  + 51380224;

static __device__ __forceinline__ u16 f2bf(float f) {
  union { float f; u32 u; } x; x.f = f;
  u32 r = 0x7fffu + ((x.u >> 16) & 1u);
  return (u16)((x.u + r) >> 16);
}

// ================= merged preprocessing: int 256 blocks | W1 128 | W2 32 | W3 1 | setup 1
__device__ __forceinline__ void int_body(const float* __restrict__ feat, float* __restrict__ S,
                                         int b, int cg, float* F)   // cg in [0,32): 32 channels
{
  int tid = threadIdx.x;
  const float* fb = feat + ((size_t)b * 1024 + cg * 32) * 361;
#pragma unroll 1
  for (int i = tid; i < 32 * 361; i += 256) F[i] = fb[i];
  __syncthreads();
  if (tid < 32) {
    int ch = tid;
    const float* fp = F + ch * 361;
    float* Sp = S + (size_t)b * 400 * 1024 + cg * 32 + ch;
    float prev[20];
#pragma unroll
    for (int w = 0; w < 20; ++w) { prev[w] = 0.f; Sp[(size_t)w * 1024] = 0.f; }
    for (int h = 0; h < 19; ++h) {
      float run = 0.f;
      float* Sr = Sp + (size_t)(h + 1) * 20 * 1024;
      Sr[0] = 0.f;
#pragma unroll
      for (int w = 0; w < 19; ++w) {
        run += fp[h * 19 + w];
        float v = run + prev[w + 1];
        Sr[(size_t)(w + 1) * 1024] = v;
        prev[w + 1] = v;
      }
    }
  }
}

__device__ __forceinline__ void packw_body(const float* __restrict__ W, u16* __restrict__ wq,
                                           int IC, int c, int og, float* F)
{
  int tid = threadIdx.x, oc0 = og * 32;
#pragma unroll 1
  for (int i = tid; i < 18432; i += 256) {
    int ocr = i / 576, r = i - ocr * 576;
    F[i] = W[(size_t)(oc0 + ocr) * IC * 9 + c * 576 + r];
  }
  __syncthreads();
#pragma unroll 1
  for (int w = tid; w < 18432; w += 256) {
    int j = w & 7, lane = (w >> 3) & 63, rest = w >> 9;
    int ntr = rest & 1, kk = rest >> 1;
    int k9i = kk >> 1, ks = kk & 1;
    int ocr = ntr * 16 + (lane & 15);
    int icr = ks * 32 + ((lane >> 4) & 3) * 8 + j;
    int bid_ = (c * 9 + k9i) * 2 + ks;
    wq[((size_t)bid_ * 1024 + (oc0 / 16 + ntr) * 64 + lane) * 8 + j] = f2bf(F[ocr * 576 + icr * 9 + k9i]);
  }
}

__global__ __launch_bounds__(256) void k_prep(
    const float* __restrict__ feat, float* __restrict__ S,
    const float* __restrict__ W1, const float* __restrict__ W2, const float* __restrict__ W3,
    u16* __restrict__ w1q, u16* __restrict__ w2q, u16* __restrict__ w3q,
    const float* __restrict__ roi, int* __restrict__ cnt,
    int* __restrict__ meta, int* __restrict__ keepd, float* __restrict__ out)
{
  __shared__ float SH[18432];                      // 73.7 KB union
  int bx = blockIdx.x;
  if (bx < 256) { int_body(feat, S, bx >> 5, bx & 31, SH); return; }
  if (bx < 384) { packw_body(W1, w1q, 1024, (bx - 256) >> 3, (bx - 256) & 7, SH); return; }   // 128 blocks: c<16
  if (bx < 416) { packw_body(W2, w2q, 256, (bx - 384) >> 3, (bx - 384) & 7, SH); return; }    // 32 blocks: c<4
  if (bx == 416) {                                 // W3 frag pack (verified R7)
    for (int i = threadIdx.x; i < 8192; i += 256) {
      int oc = i >> 8, ic = i & 255;
      int kk = ic >> 5;
      int lane = ((ic >> 3) & 3) * 16 + (oc & 15);
      int nt16 = oc >> 4;
      int j = ic & 7;
      w3q[((size_t)((kk * 2 + nt16) * 64) + lane) * 8 + j] = f2bf(W3[i]);
    }
    return;
  }
  // deterministic setup, ONE block (bx==417): all 8 batches, stable compaction, no atomics
  int t = threadIdx.x;
  int* sval = (int*)SH;
  int* spre = sval + 128;
  __shared__ int base;
  if (t == 0) base = 0;
  __syncthreads();
  for (int b = 0; b < NB; ++b) {
    int rl[4], cl[4], valid = 0;
    if (t < 128) {
      const float* rp = roi + (size_t)(b * NR + t) * 5;
#pragma unroll
      for (int j = 0; j < 4; ++j) {
        rl[j] = (int)(rp[1 + j] * 18.75f);
        cl[j] = min(max(rl[j], 0), 18);
      }
      valid = (cl[2] > cl[0]) && (cl[3] > cl[1]) ? 1 : 0;
      sval[t] = valid;
    }
    __syncthreads();
    if (t == 0) {
      int s = 0;
      for (int i = 0; i < 128; ++i) { spre[i] = s; s += sval[i]; }
      spre[128] = s;
      keepd[b] = s;
      out[OUT_KEEP + b] = (float)s;
    }
    __syncthreads();
    if (t < 128) {
      int keep = spre[128];
      if (valid) {
        int slot = base + spre[t];                 // stable global slot
        int* mt = meta + slot * 8;
        mt[0] = b; mt[1] = spre[t];
        mt[2] = cl[1]; mt[3] = cl[3];
        mt[4] = cl[0]; mt[5] = cl[2];
#pragma unroll
        for (int j = 0; j < 4; ++j)
          out[(size_t)(b * NR + spre[t]) * 4 + j] = (float)rl[j] * (16.0f / 300.0f);
      }
      if (t >= keep) {
#pragma unroll
        for (int j = 0; j < 4; ++j) out[(size_t)(b * NR + t) * 4 + j] = 0.f;
      }
    }
    __syncthreads();
    if (t == 0) base += spre[128];
    __syncthreads();
  }
  if (t == 0) *cnt = base;
}

// ---------------- k_pool: pool valid slots -> Apool[slot][16][49][64]; grid (NSLOT, 8)
__global__ __launch_bounds__(256) void k_pool(
    const int* __restrict__ cnt, const int* __restrict__ meta,
    const float* __restrict__ S, u16* __restrict__ Apool)
{
  int cv = *cnt; if (cv > NSLOT) cv = NSLOT;
  int slot = blockIdx.x;
  if (slot >= cv) return;
  const int* mt_ = meta + slot * 8;
  int b = mt_[0], ylo = mt_[2], yhi = mt_[3], xlo = mt_[4], xhi = mt_[5];
  int Hy = yhi - ylo + 1, Hx = xhi - xlo + 1;
  const float* Sb = S + (size_t)b * 400 * 1024;
  u16* Ap = Apool + (size_t)slot * 50176;
  int base = blockIdx.y * 6272, end = base + 6272;
  int tid = threadIdx.x;
#pragma unroll 1
  for (int t0 = base + tid; t0 < end; t0 += 1024) {
#pragma unroll
    for (int u = 0; u < 4; ++u) {
      int t = t0 + u * 256;
      if (t < end) {
        int ch = t & 63, r = t >> 6;
        int bin = r % 49, c = r / 49;
        int p = bin / 7, q = bin - 7 * p;
        int sy = (p * Hy) / 7, ey = ((p + 1) * Hy + 6) / 7;
        int sx = (q * Hx) / 7, ex = ((q + 1) * Hx + 6) / 7;
        int y0 = ylo + sy, y1 = ylo + ey, x0 = xlo + sx, x1 = xlo + ex;
        const float* Sc = Sb + c * 64 + ch;
        float v = Sc[(size_t)(y1 * 20 + x1) * 1024] - Sc[(size_t)(y0 * 20 + x1) * 1024]
                - Sc[(size_t)(y1 * 20 + x0) * 1024] + Sc[(size_t)(y0 * 20 + x0) * 1024];
        v /= (float)((ey - sy) * (ex - sx));
        Ap[(size_t)c * 3136 + bin * 64 + ch] = f2bf(v);
      }
    }
  }
}

// packed A-fragment offsets for a [50][STR] panel (zero row 49)
template<int STR>
__device__ __forceinline__ void build_aoffp(int n, int kq, int (&aoffp)[9][2]) {
#pragma unroll
  for (int t9 = 0; t9 < 9; ++t9) {
    int off[4];
#pragma unroll
    for (int mt = 0; mt < 4; ++mt) {
      int lm = mt * 16 + n;
      int mv = lm < 49;
      int lm2 = mv ? lm : 0;
      int p = lm2 / 7, q = lm2 - 7 * p;
      int ky = t9 / 3, kx = t9 - 3 * (t9 / 3);
      int ry = p + ky - 1, rx = q + kx - 1;
      int ok = mv && ry >= 0 && ry < 7 && rx >= 0 && rx < 7;
      int rr = ok ? ry * 7 + rx : 49;
      off[mt] = rr * STR + kq * 8;
    }
    aoffp[t9][0] = (off[0] & 0xFFFF) | (off[1] << 16);
    aoffp[t9][1] = (off[2] & 0xFFFF) | (off[3] << 16);
  }
}

// ================= conv1 (R17-exact): 4 ROIs x 64 oc; 16 waves = roi4 x och2 x kh2
__global__ __launch_bounds__(1024) void k_conv1(
    const int* __restrict__ cnt, const u16* __restrict__ Apool, const u16* __restrict__ wq,
    const float* __restrict__ bb, const float* __restrict__ gg, const float* __restrict__ bec,
    const float* __restrict__ mm, const float* __restrict__ vv,
    u16* __restrict__ x1)
{
  int cv = *cnt; if (cv > NSLOT) cv = NSLOT;
  int slot0 = blockIdx.x * 4, ocq = blockIdx.y;
  if (slot0 >= cv) return;

  __shared__ __align__(16) u16 panels[8 * 3600];    // [kh2][roi4][50][72] = 57.6 KB
  float* red = (float*)panels;

  int tid = threadIdx.x, lane = tid & 63, wave = tid >> 6;
  int roi4 = wave & 3, och = (wave >> 2) & 1, kh = wave >> 3;
  int n = lane & 15, kq = lane >> 4;

  for (int i = tid; i < 8 * 36; i += 1024) {
    int sp = i / 36, w2 = i - sp * 36;
    ((u32*)(panels + sp * 3600 + 49 * 72))[w2] = 0;
  }

  int aoffp[9][2];
  build_aoffp<72>(n, kq, aoffp);
  f32x4 acc[4][2];
#pragma unroll
  for (int i = 0; i < 4; ++i)
#pragma unroll
    for (int j = 0; j < 2; ++j) acc[i][j] = (f32x4){0.f, 0.f, 0.f, 0.f};

  const u16* pf = wq + (size_t)(ocq * 4 + och * 2) * 512 + (size_t)lane * 8
                + (size_t)(kh * 8) * 18 * 8192;
  short8 bbuf[2][2];
#pragma unroll
  for (int nt = 0; nt < 2; ++nt) bbuf[0][nt] = *(const short8*)(pf + nt * 512);
#pragma unroll
  for (int nt = 0; nt < 2; ++nt) bbuf[1][nt] = *(const short8*)(pf + 8192 + nt * 512);
  pf += (size_t)2 * 8192;

  auto stage = [&](int ca, int cb) {
#pragma unroll 1
    for (int t = tid; t < 3136; t += 1024) {
      int khs = t >= 1568 ? 1 : 0;
      int e2 = t - khs * 1568;
      int rr = e2 / 392, e = e2 - rr * 392;
      int c = khs ? cb : ca;
      int sl = slot0 + rr; if (sl >= cv) sl = cv - 1;
      uint4 v = *((const uint4*)(Apool + ((size_t)sl * 16 + c) * 3136) + e);
      *(uint4*)(panels + (size_t)(khs * 4 + rr) * 3600 + (e >> 3) * 72 + (e & 7) * 8) = v;
    }
  };

  stage(0, 8);
  __syncthreads();

  const u16* P = panels + (size_t)(kh * 4 + roi4) * 3600;
#pragma unroll 1
  for (int i = 0; i < 8; ++i) {
#pragma unroll
    for (int kk = 0; kk < 18; ++kk) {
      int t9 = kk >> 1, ks = kk & 1;
      short8 bfr[2], afr[4];
#pragma unroll
      for (int nt = 0; nt < 2; ++nt) bfr[nt] = bbuf[kk & 1][nt];
#pragma unroll
      for (int nt = 0; nt < 2; ++nt) bbuf[kk & 1][nt] = *(const short8*)(pf + nt * 512);
      pf += 8192;
      int coff = ks * 32;
      int o0 = (aoffp[t9][0] & 0xFFFF) + coff, o1 = (int)((u32)aoffp[t9][0] >> 16) + coff;
      int o2 = (aoffp[t9][1] & 0xFFFF) + coff, o3 = (int)((u32)aoffp[t9][1] >> 16) + coff;
      afr[0] = *(const short8*)(P + o0); afr[1] = *(const short8*)(P + o1);
      afr[2] = *(const short8*)(P + o2); afr[3] = *(const short8*)(P + o3);
#pragma unroll
      for (int mt = 0; mt < 4; ++mt)
#pragma unroll
        for (int nt = 0; nt < 2; ++nt)
          acc[mt][nt] = __builtin_amdgcn_mfma_f32_16x16x32_bf16(afr[mt], bfr[nt], acc[mt][nt], 0, 0, 0);
    }
    __syncthreads();
    if (i + 1 < 8) {
      stage(i + 1, 9 + i);
      __syncthreads();
    }
  }

  if (kh == 1) {
#pragma unroll
    for (int nt = 0; nt < 2; ++nt)
#pragma unroll
      for (int mt = 0; mt < 4; ++mt)
#pragma unroll
        for (int r = 0; r < 4; ++r) {
          int m = mt * 16 + kq * 4 + r;
          if (m < 49) red[(((size_t)roi4 * 2 + och) * 49 + m) * 32 + nt * 16 + n] = acc[mt][nt][r];
        }
  }
  __syncthreads();
  if (kh == 0) {
    int slot = slot0 + roi4;
    if (slot < cv) {
#pragma unroll
      for (int nt = 0; nt < 2; ++nt) {
        int oc = ocq * 64 + och * 32 + nt * 16 + n;
        float sc = gg[oc] * rsqrtf(vv[oc] + EPSV);
        float sh = (bb[oc] - mm[oc]) * sc + bec[oc];
#pragma unroll
        for (int mt = 0; mt < 4; ++mt)
#pragma unroll
          for (int r = 0; r < 4; ++r) {
            int m = mt * 16 + kq * 4 + r;
            if (m < 49) {
              float y = acc[mt][nt][r] + red[(((size_t)roi4 * 2 + och) * 49 + m) * 32 + nt * 16 + n];
              y = fmaf(y, sc, sh);
              x1[((size_t)slot * 4 + ocq) * 3136 + m * 64 + (oc & 63)] = f2bf(y > 0.f ? y : 0.f);
            }
          }
      }
    }
  }
}

// ================= conv2+conv3 fused (R17-exact, 16-wave) + zero-fill duty
__global__ __launch_bounds__(1024) void k_conv23(
    const int* __restrict__ cnt, const int* __restrict__ meta, const int* __restrict__ keepd,
    const u16* __restrict__ x1, const u16* __restrict__ w2q, const u16* __restrict__ w3q,
    const float* __restrict__ b2, const float* __restrict__ g2, const float* __restrict__ be2,
    const float* __restrict__ m2, const float* __restrict__ v2,
    const float* __restrict__ g3, const float* __restrict__ be3,
    const float* __restrict__ m3, const float* __restrict__ v3,
    float* __restrict__ out)
{
  int cv = *cnt; if (cv > NSLOT) cv = NSLOT;
  int slot = blockIdx.x;
  int tid = threadIdx.x;
  if (slot >= cv) {
    int nfill = NSLOT - cv;
#pragma unroll 1
    for (int j = slot - cv; j < 1024; j += nfill) {
      int b = j >> 7, dd = j & 127;
      if (dd >= keepd[b]) {
        float* o = out + OUT_OC + (size_t)(b * NR + dd) * 1568;
        for (int t = tid; t < 1568; t += 1024) o[t] = 0.f;
      }
    }
    return;
  }
  const int* mt_ = meta + slot * 8;
  int b = mt_[0], dst = mt_[1];

  __shared__ __align__(16) char smem[77600];
  u16*   panels = (u16*)smem;
  float* red    = (float*)smem;
  u16*   xp     = (u16*)(smem + 51200);
  float* red3   = (float*)smem;

  int lane = tid & 63, wave = tid >> 6;
  int ng = wave & 7, kh = wave >> 3;
  int n = lane & 15, kq = lane >> 4;

  for (int i = tid; i < 4 * 36; i += 1024) {
    int sp = i / 36, w2 = i - sp * 36;
    ((u32*)(panels + sp * 3600 + 49 * 72))[w2] = 0;
  }
  const u16* xs = x1 + (size_t)slot * 4 * 3136;
#pragma unroll 1
  for (int t = tid; t < 1568; t += 1024) {
    int c = t / 392, e = t - c * 392;
    uint4 v = *((const uint4*)(xs + (size_t)c * 3136) + e);
    *(uint4*)(panels + (size_t)c * 3600 + (e >> 3) * 72 + (e & 7) * 8) = v;
  }

  int aoffp[9][2];
  build_aoffp<72>(n, kq, aoffp);
  f32x4 acc[4][2];
#pragma unroll
  for (int i = 0; i < 4; ++i)
#pragma unroll
    for (int j = 0; j < 2; ++j) acc[i][j] = (f32x4){0.f, 0.f, 0.f, 0.f};

  const u16* pf = w2q + (size_t)(ng * 2) * 512 + (size_t)lane * 8 + (size_t)(kh * 36) * 8192;
  short8 bbuf[2][2];
#pragma unroll
  for (int nt = 0; nt < 2; ++nt) bbuf[0][nt] = *(const short8*)(pf + nt * 512);
#pragma unroll
  for (int nt = 0; nt < 2; ++nt) bbuf[1][nt] = *(const short8*)(pf + 8192 + nt * 512);
  pf += (size_t)2 * 8192;

  __syncthreads();

#pragma unroll 1
  for (int ci = 0; ci < 2; ++ci) {
    const u16* P = panels + (size_t)(kh * 2 + ci) * 3600;
#pragma unroll
    for (int kk = 0; kk < 18; ++kk) {
      int t9 = kk >> 1, ks = kk & 1;
      short8 bfr[2], afr[4];
#pragma unroll
      for (int nt = 0; nt < 2; ++nt) bfr[nt] = bbuf[kk & 1][nt];
#pragma unroll
      for (int nt = 0; nt < 2; ++nt) bbuf[kk & 1][nt] = *(const short8*)(pf + nt * 512);
      pf += 8192;
      int coff = ks * 32;
      int o0 = (aoffp[t9][0] & 0xFFFF) + coff, o1 = (int)((u32)aoffp[t9][0] >> 16) + coff;
      int o2 = (aoffp[t9][1] & 0xFFFF) + coff, o3 = (int)((u32)aoffp[t9][1] >> 16) + coff;
      afr[0] = *(const short8*)(P + o0); afr[1] = *(const short8*)(P + o1);
      afr[2] = *(const short8*)(P + o2); afr[3] = *(const short8*)(P + o3);
#pragma unroll
      for (int mt = 0; mt < 4; ++mt)
#pragma unroll
        for (int nt = 0; nt < 2; ++nt)
          acc[mt][nt] = __builtin_amdgcn_mfma_f32_16x16x32_bf16(afr[mt], bfr[nt], acc[mt][nt], 0, 0, 0);
    }
  }
  __syncthreads();

  if (kh == 1) {
#pragma unroll
    for (int nt = 0; nt < 2; ++nt)
#pragma unroll
      for (int mt = 0; mt < 4; ++mt)
#pragma unroll
        for (int r = 0; r < 4; ++r) {
          int m = mt * 16 + kq * 4 + r;
          if (m < 49) red[((size_t)ng * 49 + m) * 32 + nt * 16 + n] = acc[mt][nt][r];
        }
  }
  __syncthreads();
  if (kh == 0) {
#pragma unroll
    for (int nt = 0; nt < 2; ++nt) {
      int oc = ng * 32 + nt * 16 + n;
      float sc = g2[oc] * rsqrtf(v2[oc] + EPSV);
      float sh = (b2[oc] - m2[oc]) * sc + be2[oc];
#pragma unroll
      for (int mt = 0; mt < 4; ++mt)
#pragma unroll
        for (int r = 0; r < 4; ++r) {
          int m = mt * 16 + kq * 4 + r;
          if (m < 49) {
            float y = acc[mt][nt][r] + red[((size_t)ng * 49 + m) * 32 + nt * 16 + n];
            y = fmaf(y, sc, sh);
            xp[m * 264 + oc] = f2bf(y > 0.f ? y : 0.f);
          }
        }
    }
  }
  if (wave == 8) {
    for (int i = lane; i < 132; i += 64) ((u32*)(xp + 49 * 264))[i] = 0;
  }
  __syncthreads();

  if (wave < 8) {
    f32x4 a3[4][2];
#pragma unroll
    for (int mt = 0; mt < 4; ++mt) { a3[mt][0] = (f32x4){0,0,0,0}; a3[mt][1] = (f32x4){0,0,0,0}; }
    const u16* b3 = w3q + ((size_t)(wave * 2) * 64 + lane) * 8;
    short8 bf0 = *(const short8*)(b3);
    short8 bf1 = *(const short8*)(b3 + 512);
#pragma unroll
    for (int mt = 0; mt < 4; ++mt) {
      int m = mt * 16 + n;
      int row = m < 49 ? m : 49;
      short8 a = *(const short8*)(xp + row * 264 + wave * 32 + kq * 8);
      a3[mt][0] = __builtin_amdgcn_mfma_f32_16x16x32_bf16(a, bf0, a3[mt][0], 0, 0, 0);
      a3[mt][1] = __builtin_amdgcn_mfma_f32_16x16x32_bf16(a, bf1, a3[mt][1], 0, 0, 0);
    }
#pragma unroll
    for (int nt = 0; nt < 2; ++nt)
#pragma unroll
      for (int mt = 0; mt < 4; ++mt)
#pragma unroll
        for (int r = 0; r < 4; ++r) {
          int m = mt * 16 + kq * 4 + r;
          if (m < 49) red3[((size_t)wave * 49 + m) * 32 + nt * 16 + n] = a3[mt][nt][r];
        }
  }
  __syncthreads();

  size_t ob = OUT_OC + ((size_t)(b * NR + dst) * 32) * 49;
#pragma unroll 1
  for (int t = tid; t < 1568; t += 1024) {
    int m = t >> 5, oc = t & 31;
    float s = 0.f;
#pragma unroll
    for (int w8 = 0; w8 < 8; ++w8) s += red3[((size_t)w8 * 49 + m) * 32 + oc];
    float sc = g3[oc] * rsqrtf(v3[oc] + EPSV);
    float y = fmaf(s, sc, be3[oc] - m3[oc] * sc);
    out[ob + (size_t)oc * 49 + m] = y > 0.f ? y : 0.f;
  }
}

extern "C" void kernel_launch(void* const* d_in, const int* in_sizes, int n_in,
                              void* d_out, int out_size, void* d_ws, size_t ws_size,
                              hipStream_t stream)
{
  (void)in_sizes; (void)n_in; (void)out_size;
  if (ws_size < WS_NEED) return;

  const float* roi  = (const float*)d_in[0];
  const float* feat = (const float*)d_in[1];
  const float* W1   = (const float*)d_in[2];
  const float* b1   = (const float*)d_in[3];
  const float* g1   = (const float*)d_in[4];
  const float* be1  = (const float*)d_in[5];
  const float* m1   = (const float*)d_in[6];
  const float* v1   = (const float*)d_in[7];
  const float* W2   = (const float*)d_in[8];
  const float* b2   = (const float*)d_in[9];
  const float* g2   = (const float*)d_in[10];
  const float* be2  = (const float*)d_in[11];
  const float* m2   = (const float*)d_in[12];
  const float* v2   = (const float*)d_in[13];
  const float* W3   = (const float*)d_in[14];
  const float* g3   = (const float*)d_in[15];
  const float* be3  = (const float*)d_in[16];
  const float* m3   = (const float*)d_in[17];
  const float* v3   = (const float*)d_in[18];

  char* ws    = (char*)d_ws;
  int*  cnt   = (int*)ws;
  int*  meta  = (int*)(ws + OFF_META);
  int*  keepd = (int*)(ws + OFF_KEEP);
  u16*  w1q   = (u16*)(ws + OFF_W1Q);
  u16*  w2q   = (u16*)(ws + OFF_W2Q);
  u16*  w3q   = (u16*)(ws + OFF_W3);
  float* S    = (float*)(ws + OFF_X1S);
  u16*  x1    = (u16*)(ws + OFF_X1S);     // x1 overwrites S after k_pool
  u16*  Apool = (u16*)(ws + OFF_AP);
  float* out  = (float*)d_out;

  k_prep<<<418, 256, 0, stream>>>(feat, S, W1, W2, W3, w1q, w2q, w3q,
                                  roi, cnt, meta, keepd, out);
  k_pool<<<dim3(NSLOT, 8), 256, 0, stream>>>(cnt, meta, S, Apool);
  k_conv1<<<dim3(NSLOT / 4, 4), 1024, 0, stream>>>(cnt, Apool, w1q, b1, g1, be1, m1, v1, x1);
  k_conv23<<<NSLOT, 1024, 0, stream>>>(cnt, meta, keepd, x1, w2q, w3q,
                                       b2, g2, be2, m2, v2, g3, be3, m3, v3, out);
}